// Round 19
// baseline (118.875 us; speedup 1.0000x reference)
//
#include <hip/hip_runtime.h>
#include <math.h>

#define DIM 128
#define NEG_BIG (-3.0e38f)
#define THRESH 20.0f         // survivors: lg >= M-20 -> dropped numerator mass
                             // <= 2e5 * 2e-9 * |v|max ~ 4e-4 << 3.17e-2 threshold
#define NB 512               // accum blocks = partial count

typedef float vf4 __attribute__((ext_vector_type(4)));   // native vector for
                                                         // __builtin_nontemporal_load

// ---------------------------------------------------------------------------
// Pass 1: logits, KEYS ONLY, strided-interleaved walk (R14-proven config).
// Quad layout: 4 lanes/row, 16 rows/chunk; lane sums |k-q| over its 32 cols
// (8x float4), 2 shfl_xor fold the quad. Walk c += P: all P waves sweep one
// contiguous ~16MB window together (DRAM locality). 2 chunks unrolled. Key
// loads NON-TEMPORAL (streamed once; keeps L2 for logits/wsmax). Per-wave
// max -> wsmax (no atomics).
// ---------------------------------------------------------------------------
__global__ __launch_bounds__(256) void nd_logits(const float* __restrict__ query,
                                                 const float* __restrict__ keys,
                                                 float* __restrict__ logits,
                                                 float* __restrict__ wsmax,
                                                 int nrows, int nchunks, int P) {
    const int tid  = threadIdx.x;
    const int lane = tid & 63;
    const int quad = lane & 3;
    const int rsub = lane >> 2;                       // 0..15
    const int wid  = blockIdx.x * (blockDim.x >> 6) + (tid >> 6);

    vf4 qv[8];
    #pragma unroll
    for (int j = 0; j < 8; ++j)
        qv[j] = *reinterpret_cast<const vf4*>(query + quad * 4 + j * 16);

    float wmax = NEG_BIG;

    #define LBODY(cc)                                                             \
        {                                                                         \
            const int  row = (cc) * 16 + rsub;                                    \
            const bool ok  = row < nrows;                                         \
            const int  rr  = ok ? row : (nrows - 1);                              \
            const float* kp = keys + (size_t)rr * DIM + quad * 4;                 \
            float s = 0.f;                                                        \
            _Pragma("unroll")                                                     \
            for (int j = 0; j < 8; ++j) {                                         \
                const vf4 k = __builtin_nontemporal_load(                         \
                                  reinterpret_cast<const vf4*>(kp + j * 16));     \
                s += fabsf(k.x - qv[j].x) + fabsf(k.y - qv[j].y)                  \
                   + fabsf(k.z - qv[j].z) + fabsf(k.w - qv[j].w);                 \
            }                                                                     \
            s += __shfl_xor(s, 1, 64);                                            \
            s += __shfl_xor(s, 2, 64);                                            \
            const float lg = ok ? -s : NEG_BIG;                                   \
            wmax = fmaxf(wmax, lg);                                               \
            if (quad == 0 && ok) logits[row] = lg;                                \
        }

    int c = wid;
    for (; c + P < nchunks; c += 2 * P) {
        LBODY(c)
        LBODY(c + P)
    }
    if (c < nchunks) LBODY(c)
    #undef LBODY

    // wmax is quad-uniform: reduce over rsub only.
    #pragma unroll
    for (int off = 4; off < 64; off <<= 1)
        wmax = fmaxf(wmax, __shfl_xor(wmax, off, 64));
    if (lane == 0) wsmax[wid] = wmax;
}

// ---------------------------------------------------------------------------
// Pass 2: sparse weighted accumulation + LAST-BLOCK final reduce.
// maxred inlined per block (deterministic). Each wave scans 64 logits/iter,
// sums w for ALL rows (exact denominator); survivors (lg >= M-THRESH) get
// cooperative 512B value-row loads, two in flight. Partials stored
// TRANSPOSED (L_part[NB], accT[d*NB+b]). Then release-fence + completion
// counter; the single last block acquire-fences and reduces partials to
// out[128] in fixed order (deterministic). No spinning, no co-residency need.
// ---------------------------------------------------------------------------
__global__ __launch_bounds__(256) void nd_accum(const float* __restrict__ values,
                                                const float* __restrict__ logits,
                                                const float* __restrict__ wsmax,
                                                float* __restrict__ L_part,
                                                float* __restrict__ accT,
                                                unsigned int* __restrict__ ctr,
                                                float* __restrict__ out,
                                                int nrows, int P, int NW) {
    __shared__ float lds[4 * DIM];
    __shared__ float sh4[4];
    __shared__ float shM;
    __shared__ unsigned int isLast;
    const int tid  = threadIdx.x;
    const int lane = tid & 63;
    const int wib  = tid >> 6;
    const int wid  = blockIdx.x * 4 + wib;

    // Inline deterministic global-max reduce over the P per-wave maxima.
    float m = NEG_BIG;
    for (int i = tid; i < P; i += 256) m = fmaxf(m, wsmax[i]);
    #pragma unroll
    for (int off = 1; off < 64; off <<= 1)
        m = fmaxf(m, __shfl_xor(m, off, 64));
    if (lane == 0) sh4[wib] = m;
    __syncthreads();
    if (tid == 0) shM = fmaxf(fmaxf(sh4[0], sh4[1]), fmaxf(sh4[2], sh4[3]));
    __syncthreads();
    const float M   = shM;
    const float cut = M - THRESH;

    float  l = 0.f;
    float2 acc = make_float2(0.f, 0.f);

    for (int base = wid * 64; base < nrows; base += NW * 64) {
        const int  row   = base + lane;
        const bool valid = row < nrows;
        const float lg   = valid ? logits[row] : NEG_BIG;
        const float w    = __expf(lg - M);            // underflows to 0 for NEG_BIG
        l += w;
        unsigned long long ball = __ballot(valid && lg >= cut);
        while (ball) {
            const int b1 = __builtin_ctzll(ball); ball &= ball - 1;
            int b2 = -1;
            if (ball) { b2 = __builtin_ctzll(ball); ball &= ball - 1; }
            const float  w1 = __shfl(w, b1, 64);
            const float2 v1 = *reinterpret_cast<const float2*>(
                                  values + (size_t)(base + b1) * DIM + lane * 2);
            float  w2 = 0.f;
            float2 v2 = make_float2(0.f, 0.f);
            if (b2 >= 0) {
                w2 = __shfl(w, b2, 64);
                v2 = *reinterpret_cast<const float2*>(
                         values + (size_t)(base + b2) * DIM + lane * 2);
            }
            acc.x += w1 * v1.x + w2 * v2.x;
            acc.y += w1 * v1.y + w2 * v2.y;
        }
    }

    // Reduce l over the wave, then block-reduce (l, acc) via LDS; publish.
    #pragma unroll
    for (int off = 1; off < 64; off <<= 1)
        l += __shfl_xor(l, off, 64);

    lds[wib * DIM + lane * 2]     = acc.x;
    lds[wib * DIM + lane * 2 + 1] = acc.y;
    if (lane == 0) sh4[wib] = l;
    __syncthreads();

    if (tid == 0) L_part[blockIdx.x] = sh4[0] + sh4[1] + sh4[2] + sh4[3];
    if (tid < DIM)
        accT[(size_t)tid * NB + blockIdx.x] =
            lds[tid] + lds[DIM + tid] + lds[2 * DIM + tid] + lds[3 * DIM + tid];

    // ---- completion counter: last block performs the final reduce ----
    __threadfence();                                  // release partials
    __syncthreads();                                  // all stores issued
    if (tid == 0) {
        const unsigned int old = atomicAdd(ctr, 1u);
        isLast = (old == (unsigned int)(gridDim.x - 1)) ? 1u : 0u;
    }
    __syncthreads();
    if (isLast == 0u) return;
    __threadfence();                                  // acquire partials

    // Every wave computes L redundantly (identical fixed order -> same bits).
    float lp = 0.f;
    #pragma unroll
    for (int k = 0; k < 8; ++k) lp += L_part[lane + 64 * k];
    #pragma unroll
    for (int off = 1; off < 64; off <<= 1)
        lp += __shfl_xor(lp, off, 64);
    const float L = lp;

    // Wave wib reduces dims d = wib, wib+4, ... (32 dims per wave).
    for (int d = wib; d < DIM; d += 4) {
        const float* row = accT + (size_t)d * NB;
        float o = 0.f;
        #pragma unroll
        for (int k = 0; k < 8; ++k) o += row[lane + 64 * k];
        #pragma unroll
        for (int off = 1; off < 64; off <<= 1)
            o += __shfl_xor(o, off, 64);
        if (lane == 0) out[d] = o / L;
    }
}

extern "C" void kernel_launch(void* const* d_in, const int* in_sizes, int n_in,
                              void* d_out, int out_size, void* d_ws, size_t ws_size,
                              hipStream_t stream) {
    const float* query  = (const float*)d_in[0];
    const float* keys   = (const float*)d_in[1];
    const float* values = (const float*)d_in[2];
    float* out = (float*)d_out;
    float* ws  = (float*)d_ws;

    const int nrows   = in_sizes[1] / DIM;
    const int nchunks = (nrows + 15) / 16;
    const int LN      = (nrows + 63) & ~63;          // logits region (floats)

    const int P  = 2048;                             // logits waves (512 blocks)
    const int NW = NB * 4;                           // accum waves (512 blocks x 4)

    float*        logits = ws;
    float*        wsmax  = ws + LN;
    float*        L_part = wsmax + ((P + 15) & ~15);
    float*        accT   = L_part + NB;
    unsigned int* ctr    = (unsigned int*)(accT + (size_t)DIM * NB);

    hipMemsetAsync(ctr, 0, sizeof(unsigned int), stream);
    nd_logits<<<P / 4, 256, 0, stream>>>(query, keys, logits, wsmax, nrows, nchunks, P);
    nd_accum <<<NB,    256, 0, stream>>>(values, logits, wsmax, L_part, accT, ctr, out,
                                         nrows, P, NW);
}

// Round 20
// 42.196 us; speedup vs baseline: 2.8172x; 2.8172x over previous
//
#include <hip/hip_runtime.h>
#include <math.h>

#define DIM 128
#define NEG_BIG (-3.0e38f)
#define THRESH 20.0f         // survivors: lg >= M-20 -> dropped numerator mass
                             // <= 2e5 * 2e-9 * |v|max ~ 4e-4 << 3.17e-2 threshold
#define NB 512               // accum blocks = partial count

typedef float vf4 __attribute__((ext_vector_type(4)));   // native vector for
                                                         // __builtin_nontemporal_load

// ---------------------------------------------------------------------------
// Pass 1: logits, KEYS ONLY, XCD-SLICED interleaved walk.
// Blocks map to XCDs round-robin (bid & 7). XCD x owns the contiguous slice
// [nchunks*x/8, nchunks*(x+1)/8); its 256 waves sweep the slice interleaved
// (c += PX), so each XCD's L2/fabric sees ONE contiguous moving window in its
// own address range. Quad layout: 4 lanes/row, 16 rows/chunk; lane sums |k-q|
// over its 32 cols (8x float4 nt-loads), 2 shfl_xor fold the quad. 2 chunks
// unrolled. Per-wave max -> wsmax (no atomics). Bitwise-identical output to
// the shared-window walk (each row computed by exactly one wave; fmax exact).
// ---------------------------------------------------------------------------
__global__ __launch_bounds__(256) void nd_logits(const float* __restrict__ query,
                                                 const float* __restrict__ keys,
                                                 float* __restrict__ logits,
                                                 float* __restrict__ wsmax,
                                                 int nrows, int nchunks, int P) {
    const int tid  = threadIdx.x;
    const int lane = tid & 63;
    const int quad = lane & 3;
    const int rsub = lane >> 2;                       // 0..15
    const int wib  = tid >> 6;
    const int wid  = blockIdx.x * 4 + wib;            // global wave id (wsmax slot)

    const int xcd  = blockIdx.x & 7;                  // XCD id (round-robin, m09)
    const int lb   = blockIdx.x >> 3;                 // local block within XCD
    const int PX   = P / 8;                           // waves per XCD (256)
    const int lwid = lb * 4 + wib;                    // local wave within XCD
    const int s0   = (int)(((long long)nchunks * xcd)       >> 3);
    const int s1   = (int)(((long long)nchunks * (xcd + 1)) >> 3);

    vf4 qv[8];
    #pragma unroll
    for (int j = 0; j < 8; ++j)
        qv[j] = *reinterpret_cast<const vf4*>(query + quad * 4 + j * 16);

    float wmax = NEG_BIG;

    #define LBODY(cc)                                                             \
        {                                                                         \
            const int  row = (cc) * 16 + rsub;                                    \
            const bool ok  = row < nrows;                                         \
            const int  rr  = ok ? row : (nrows - 1);                              \
            const float* kp = keys + (size_t)rr * DIM + quad * 4;                 \
            float s = 0.f;                                                        \
            _Pragma("unroll")                                                     \
            for (int j = 0; j < 8; ++j) {                                         \
                const vf4 k = __builtin_nontemporal_load(                         \
                                  reinterpret_cast<const vf4*>(kp + j * 16));     \
                s += fabsf(k.x - qv[j].x) + fabsf(k.y - qv[j].y)                  \
                   + fabsf(k.z - qv[j].z) + fabsf(k.w - qv[j].w);                 \
            }                                                                     \
            s += __shfl_xor(s, 1, 64);                                            \
            s += __shfl_xor(s, 2, 64);                                            \
            const float lg = ok ? -s : NEG_BIG;                                   \
            wmax = fmaxf(wmax, lg);                                               \
            if (quad == 0 && ok) logits[row] = lg;                                \
        }

    int c = s0 + lwid;
    for (; c + PX < s1; c += 2 * PX) {
        LBODY(c)
        LBODY(c + PX)
    }
    if (c < s1) LBODY(c)
    #undef LBODY

    // wmax is quad-uniform: reduce over rsub only.
    #pragma unroll
    for (int off = 4; off < 64; off <<= 1)
        wmax = fmaxf(wmax, __shfl_xor(wmax, off, 64));
    if (lane == 0) wsmax[wid] = wmax;
}

// ---------------------------------------------------------------------------
// Pass 2: sparse weighted accumulation, maxred INLINED per block (R18-proven).
// Every block reduces wsmax[P] identically (bitwise-deterministic M). Each
// wave scans 64 logits/iter (coalesced 256B), sums w = exp(lg-M) for ALL rows
// (exact denominator); survivors (lg >= M-THRESH, <~1%) get cooperative 512B
// value-row loads, two in flight. Partials stored TRANSPOSED: L_part[NB],
// accT[d*NB + b] so the final kernel reads contiguous rows.
// ---------------------------------------------------------------------------
__global__ __launch_bounds__(256) void nd_accum(const float* __restrict__ values,
                                                const float* __restrict__ logits,
                                                const float* __restrict__ wsmax,
                                                float* __restrict__ L_part,
                                                float* __restrict__ accT,
                                                int nrows, int P, int NW) {
    __shared__ float lds[4 * DIM];
    __shared__ float sh4[4];
    __shared__ float shM;
    const int tid  = threadIdx.x;
    const int lane = tid & 63;
    const int wib  = tid >> 6;
    const int wid  = blockIdx.x * 4 + wib;

    // Inline deterministic global-max reduce over the P per-wave maxima.
    float m = NEG_BIG;
    for (int i = tid; i < P; i += 256) m = fmaxf(m, wsmax[i]);
    #pragma unroll
    for (int off = 1; off < 64; off <<= 1)
        m = fmaxf(m, __shfl_xor(m, off, 64));
    if (lane == 0) sh4[wib] = m;
    __syncthreads();
    if (tid == 0) shM = fmaxf(fmaxf(sh4[0], sh4[1]), fmaxf(sh4[2], sh4[3]));
    __syncthreads();
    const float M   = shM;
    const float cut = M - THRESH;

    float  l = 0.f;
    float2 acc = make_float2(0.f, 0.f);

    for (int base = wid * 64; base < nrows; base += NW * 64) {
        const int  row   = base + lane;
        const bool valid = row < nrows;
        const float lg   = valid ? logits[row] : NEG_BIG;
        const float w    = __expf(lg - M);            // underflows to 0 for NEG_BIG
        l += w;
        unsigned long long ball = __ballot(valid && lg >= cut);
        while (ball) {
            const int b1 = __builtin_ctzll(ball); ball &= ball - 1;
            int b2 = -1;
            if (ball) { b2 = __builtin_ctzll(ball); ball &= ball - 1; }
            const float  w1 = __shfl(w, b1, 64);
            const float2 v1 = *reinterpret_cast<const float2*>(
                                  values + (size_t)(base + b1) * DIM + lane * 2);
            float  w2 = 0.f;
            float2 v2 = make_float2(0.f, 0.f);
            if (b2 >= 0) {
                w2 = __shfl(w, b2, 64);
                v2 = *reinterpret_cast<const float2*>(
                         values + (size_t)(base + b2) * DIM + lane * 2);
            }
            acc.x += w1 * v1.x + w2 * v2.x;
            acc.y += w1 * v1.y + w2 * v2.y;
        }
    }

    // Reduce l over the wave, then block-reduce (l, acc) via LDS.
    #pragma unroll
    for (int off = 1; off < 64; off <<= 1)
        l += __shfl_xor(l, off, 64);

    lds[wib * DIM + lane * 2]     = acc.x;
    lds[wib * DIM + lane * 2 + 1] = acc.y;
    if (lane == 0) sh4[wib] = l;
    __syncthreads();

    if (tid == 0) L_part[blockIdx.x] = sh4[0] + sh4[1] + sh4[2] + sh4[3];
    if (tid < DIM)
        accT[(size_t)tid * NB + blockIdx.x] =
            lds[tid] + lds[DIM + tid] + lds[2 * DIM + tid] + lds[3 * DIM + tid];
}

// ---------------------------------------------------------------------------
// Final: 128 blocks, one per output dim. Block d reduces its contiguous accT
// row (512 floats, 2 coalesced loads/thread) and the shared L row, writes
// out[d] = sum / L. Fixed reduction order -> deterministic.
// ---------------------------------------------------------------------------
__global__ __launch_bounds__(256) void nd_final(const float* __restrict__ L_part,
                                                const float* __restrict__ accT,
                                                float* __restrict__ out) {
    __shared__ float shw[4];
    __shared__ float shl[4];
    const int tid  = threadIdx.x;
    const int lane = tid & 63;
    const int wib  = tid >> 6;
    const int d    = blockIdx.x;

    float lp = L_part[tid] + L_part[tid + 256];
    float o  = accT[(size_t)d * NB + tid] + accT[(size_t)d * NB + tid + 256];
    #pragma unroll
    for (int off = 1; off < 64; off <<= 1) {
        lp += __shfl_xor(lp, off, 64);
        o  += __shfl_xor(o,  off, 64);
    }
    if (lane == 0) { shw[wib] = o; shl[wib] = lp; }
    __syncthreads();
    if (tid == 0) {
        const float L = shl[0] + shl[1] + shl[2] + shl[3];
        out[d] = (shw[0] + shw[1] + shw[2] + shw[3]) / L;
    }
}

extern "C" void kernel_launch(void* const* d_in, const int* in_sizes, int n_in,
                              void* d_out, int out_size, void* d_ws, size_t ws_size,
                              hipStream_t stream) {
    const float* query  = (const float*)d_in[0];
    const float* keys   = (const float*)d_in[1];
    const float* values = (const float*)d_in[2];
    float* out = (float*)d_out;
    float* ws  = (float*)d_ws;

    const int nrows   = in_sizes[1] / DIM;
    const int nchunks = (nrows + 15) / 16;
    const int LN      = (nrows + 63) & ~63;          // logits region (floats)

    const int P  = 2048;                             // logits waves (512 blocks)
    const int NW = NB * 4;                           // accum waves (512 blocks x 4)

    float* logits = ws;
    float* wsmax  = ws + LN;
    float* L_part = wsmax + ((P + 15) & ~15);
    float* accT   = L_part + NB;

    nd_logits<<<P / 4, 256, 0, stream>>>(query, keys, logits, wsmax, nrows, nchunks, P);
    nd_accum <<<NB,    256, 0, stream>>>(values, logits, wsmax, L_part, accT, nrows, P, NW);
    nd_final <<<DIM,   256, 0, stream>>>(L_part, accT, out);
}